// Round 1
// baseline (8657.044 us; speedup 1.0000x reference)
//
#include <hip/hip_runtime.h>
#include <math.h>

// Problem constants (fixed by the reference file)
#define NN 100000   // nodes
#define DD 128      // feature dim
#define EE 600000   // edges
#define RR 5        // relations
#define BR 64       // GEMM rows per block
#define APAD 4      // LDS row pad (keeps float4 alignment: (128+4)*4B % 16 == 0)

__device__ __forceinline__ float gelu_exact(float v) {
    return 0.5f * v * (1.0f + erff(v * 0.7071067811865476f));
}

// ---------------------------------------------------------------------------
// Fused GEMM: for a 64-row slab of x, computes three 128-col outputs:
//   out0 = x @ Wa            (cols 0..127 of Wa, row stride sa)
//   out1 = x @ Wf[:, 0:128]  (+ bias[0:128] if bias)      -> beta
//   out2 = x @ Wf[:, 128:256](+ bias[128:256] if bias)    -> gamma
// 256 threads, 8x4 microtile per thread, A-tile + half-K W chunk in LDS.
// ---------------------------------------------------------------------------
__global__ __launch_bounds__(256, 2)
void film_gemm(const float* __restrict__ x,
               const float* __restrict__ Wa, int sa,
               const float* __restrict__ Wf, int sf,
               const float* __restrict__ bias,
               float* __restrict__ out0,
               float* __restrict__ out1,
               float* __restrict__ out2)
{
    __shared__ float As[BR][DD + APAD];
    __shared__ float Ws[64][DD];
    const int tid  = threadIdx.x;
    const int tx   = tid & 31;      // col group: cols tx*4..tx*4+3
    const int ty   = tid >> 5;      // row group: rows ty*8..ty*8+7
    const int row0 = blockIdx.x * BR;
    const int c0   = tx * 4;

    // Stage A tile (64 x 128), zero-fill tail rows
    #pragma unroll
    for (int it = 0; it < 8; ++it) {
        int r = it * 8 + ty;
        int row = row0 + r;
        float4 v = make_float4(0.f, 0.f, 0.f, 0.f);
        if (row < NN) v = *(const float4*)(x + (size_t)row * DD + c0);
        *(float4*)&As[r][c0] = v;
    }
    __syncthreads();

    for (int t = 0; t < 3; ++t) {
        const float* W  = (t == 0) ? Wa : Wf;
        const int ws_   = (t == 0) ? sa : sf;
        const int cofs  = (t == 2) ? DD : 0;

        float acc[8][4];
        #pragma unroll
        for (int i = 0; i < 8; ++i)
            #pragma unroll
            for (int j = 0; j < 4; ++j) acc[i][j] = 0.f;

        for (int kc = 0; kc < DD; kc += 64) {
            // stage 64x128 W chunk
            #pragma unroll
            for (int it = 0; it < 8; ++it) {
                int idx = it * 256 + tid;
                int kk  = idx >> 5;
                int cc  = (idx & 31) * 4;
                *(float4*)&Ws[kk][cc] =
                    *(const float4*)(W + (size_t)(kc + kk) * ws_ + cofs + cc);
            }
            __syncthreads();
            #pragma unroll
            for (int k = 0; k < 64; k += 4) {
                float4 w0 = *(const float4*)&Ws[k + 0][c0];
                float4 w1 = *(const float4*)&Ws[k + 1][c0];
                float4 w2 = *(const float4*)&Ws[k + 2][c0];
                float4 w3 = *(const float4*)&Ws[k + 3][c0];
                #pragma unroll
                for (int i = 0; i < 8; ++i) {
                    float4 a = *(const float4*)&As[ty * 8 + i][kc + k];
                    acc[i][0] += a.x * w0.x + a.y * w1.x + a.z * w2.x + a.w * w3.x;
                    acc[i][1] += a.x * w0.y + a.y * w1.y + a.z * w2.y + a.w * w3.y;
                    acc[i][2] += a.x * w0.z + a.y * w1.z + a.z * w2.z + a.w * w3.z;
                    acc[i][3] += a.x * w0.w + a.y * w1.w + a.z * w2.w + a.w * w3.w;
                }
            }
            __syncthreads();
        }

        float b0 = 0.f, b1 = 0.f, b2 = 0.f, b3 = 0.f;
        if (bias != nullptr && t > 0) {
            b0 = bias[cofs + c0 + 0];
            b1 = bias[cofs + c0 + 1];
            b2 = bias[cofs + c0 + 2];
            b3 = bias[cofs + c0 + 3];
        }
        float* outp = (t == 0) ? out0 : (t == 1) ? out1 : out2;
        #pragma unroll
        for (int i = 0; i < 8; ++i) {
            int row = row0 + ty * 8 + i;
            if (row < NN) {
                float4 v = make_float4(acc[i][0] + b0, acc[i][1] + b1,
                                       acc[i][2] + b2, acc[i][3] + b3);
                *(float4*)(outp + (size_t)row * DD + c0) = v;
            }
        }
    }
}

// ---------------------------------------------------------------------------
// Final GEMM: out = gelu(A) @ W + bias   (gelu applied while staging A)
// ---------------------------------------------------------------------------
__global__ __launch_bounds__(256, 2)
void final_gemm(const float* __restrict__ A,
                const float* __restrict__ W,
                const float* __restrict__ bias,
                float* __restrict__ out)
{
    __shared__ float As[BR][DD + APAD];
    __shared__ float Ws[64][DD];
    const int tid  = threadIdx.x;
    const int tx   = tid & 31;
    const int ty   = tid >> 5;
    const int row0 = blockIdx.x * BR;
    const int c0   = tx * 4;

    #pragma unroll
    for (int it = 0; it < 8; ++it) {
        int r = it * 8 + ty;
        int row = row0 + r;
        float4 v = make_float4(0.f, 0.f, 0.f, 0.f);
        if (row < NN) {
            v = *(const float4*)(A + (size_t)row * DD + c0);
            v.x = gelu_exact(v.x); v.y = gelu_exact(v.y);
            v.z = gelu_exact(v.z); v.w = gelu_exact(v.w);
        }
        *(float4*)&As[r][c0] = v;
    }
    __syncthreads();

    float acc[8][4];
    #pragma unroll
    for (int i = 0; i < 8; ++i)
        #pragma unroll
        for (int j = 0; j < 4; ++j) acc[i][j] = 0.f;

    for (int kc = 0; kc < DD; kc += 64) {
        #pragma unroll
        for (int it = 0; it < 8; ++it) {
            int idx = it * 256 + tid;
            int kk  = idx >> 5;
            int cc  = (idx & 31) * 4;
            *(float4*)&Ws[kk][cc] = *(const float4*)(W + (size_t)(kc + kk) * DD + cc);
        }
        __syncthreads();
        #pragma unroll
        for (int k = 0; k < 64; k += 4) {
            float4 w0 = *(const float4*)&Ws[k + 0][c0];
            float4 w1 = *(const float4*)&Ws[k + 1][c0];
            float4 w2 = *(const float4*)&Ws[k + 2][c0];
            float4 w3 = *(const float4*)&Ws[k + 3][c0];
            #pragma unroll
            for (int i = 0; i < 8; ++i) {
                float4 a = *(const float4*)&As[ty * 8 + i][kc + k];
                acc[i][0] += a.x * w0.x + a.y * w1.x + a.z * w2.x + a.w * w3.x;
                acc[i][1] += a.x * w0.y + a.y * w1.y + a.z * w2.y + a.w * w3.y;
                acc[i][2] += a.x * w0.z + a.y * w1.z + a.z * w2.z + a.w * w3.z;
                acc[i][3] += a.x * w0.w + a.y * w1.w + a.z * w2.w + a.w * w3.w;
            }
        }
        __syncthreads();
    }

    const float b0 = bias[c0 + 0], b1 = bias[c0 + 1], b2 = bias[c0 + 2], b3 = bias[c0 + 3];
    #pragma unroll
    for (int i = 0; i < 8; ++i) {
        int row = row0 + ty * 8 + i;
        if (row < NN) {
            float4 v = make_float4(acc[i][0] + b0, acc[i][1] + b1,
                                   acc[i][2] + b2, acc[i][3] + b3);
            *(float4*)(out + (size_t)row * DD + c0) = v;
        }
    }
}

// out_acc = relu(gamma * xl + beta)   elementwise over N*D
__global__ __launch_bounds__(256)
void skip_combine(const float* __restrict__ xl, const float* __restrict__ beta,
                  const float* __restrict__ gamma, float* __restrict__ out_acc)
{
    size_t i = ((size_t)blockIdx.x * 256 + threadIdx.x) * 4;
    float4 xv = *(const float4*)(xl + i);
    float4 bv = *(const float4*)(beta + i);
    float4 gv = *(const float4*)(gamma + i);
    float4 o;
    o.x = fmaxf(gv.x * xv.x + bv.x, 0.f);
    o.y = fmaxf(gv.y * xv.y + bv.y, 0.f);
    o.z = fmaxf(gv.z * xv.z + bv.z, 0.f);
    o.w = fmaxf(gv.w * xv.w + bv.w, 0.f);
    *(float4*)(out_acc + i) = o;
}

// per-(relation,dst) in-degree counts
__global__ __launch_bounds__(256)
void count_kernel(const int* __restrict__ ei, const int* __restrict__ et,
                  float* __restrict__ cnt)
{
    int e = blockIdx.x * 256 + threadIdx.x;
    if (e < EE) {
        int r = et[e];
        int d = ei[EE + e];
        atomicAdd(&cnt[(size_t)r * NN + d], 1.0f);
    }
}

// one 32-lane group per edge; gathers xl[src], gamma/beta[dst], scatters
// relu(g*xl+b)/cnt into out_acc[dst] with atomics. Skips edges of other types.
__global__ __launch_bounds__(256)
void edge_pass(const int* __restrict__ ei, const int* __restrict__ et, int rel,
               const float* __restrict__ xl, const float* __restrict__ beta,
               const float* __restrict__ gamma, const float* __restrict__ cnt,
               float* __restrict__ out_acc)
{
    int e = blockIdx.x * 8 + (threadIdx.x >> 5);
    if (e >= EE) return;
    if (et[e] != rel) return;
    int src = ei[e];
    int dst = ei[EE + e];
    int c = (threadIdx.x & 31) * 4;
    float inv = 1.0f / fmaxf(cnt[(size_t)rel * NN + dst], 1.0f);
    float4 xs = *(const float4*)(xl + (size_t)src * DD + c);
    float4 gv = *(const float4*)(gamma + (size_t)dst * DD + c);
    float4 bv = *(const float4*)(beta + (size_t)dst * DD + c);
    float m0 = fmaxf(gv.x * xs.x + bv.x, 0.f) * inv;
    float m1 = fmaxf(gv.y * xs.y + bv.y, 0.f) * inv;
    float m2 = fmaxf(gv.z * xs.z + bv.z, 0.f) * inv;
    float m3 = fmaxf(gv.w * xs.w + bv.w, 0.f) * inv;
    float* dp = out_acc + (size_t)dst * DD + c;
    atomicAdd(dp + 0, m0);
    atomicAdd(dp + 1, m1);
    atomicAdd(dp + 2, m2);
    atomicAdd(dp + 3, m3);
}

extern "C" void kernel_launch(void* const* d_in, const int* in_sizes, int n_in,
                              void* d_out, int out_size, void* d_ws, size_t ws_size,
                              hipStream_t stream)
{
    const float* x           = (const float*)d_in[0];
    const int*   ei          = (const int*)d_in[1];   // [2,E] row-major: src then dst
    const int*   et          = (const int*)d_in[2];
    const float* lin_skip_w  = (const float*)d_in[3]; // (D,D)
    const float* film_skip_w = (const float*)d_in[4]; // (D,2D)
    const float* lins_w      = (const float*)d_in[5]; // (R,D,D)
    const float* films_w     = (const float*)d_in[6]; // (R,D,2D)
    const float* films_b     = (const float*)d_in[7]; // (R,2D)
    const float* linear1_w   = (const float*)d_in[8]; // (D,D)
    const float* linear1_b   = (const float*)d_in[9]; // (D,)
    float* out = (float*)d_out;
    float* ws  = (float*)d_ws;

    const size_t ND = (size_t)NN * DD;
    // workspace layout (floats): out_acc | xl | beta | gamma | cnt  (~207 MB)
    float* out_acc = ws;
    float* xl      = ws + ND;
    float* beta    = ws + 2 * ND;
    float* gamma   = ws + 3 * ND;
    float* cnt     = ws + 4 * ND;

    const int gemm_grid = (NN + BR - 1) / BR;   // 1563

    hipMemsetAsync(cnt, 0, (size_t)RR * NN * sizeof(float), stream);
    count_kernel<<<(EE + 255) / 256, 256, 0, stream>>>(ei, et, cnt);

    // skip path: xl = x@lin_skip_w, beta/gamma = x@film_skip_w (no bias)
    film_gemm<<<gemm_grid, 256, 0, stream>>>(x, lin_skip_w, DD, film_skip_w, 2 * DD,
                                             nullptr, xl, beta, gamma);
    skip_combine<<<(int)(ND / 1024), 256, 0, stream>>>(xl, beta, gamma, out_acc);

    for (int r = 0; r < RR; ++r) {
        film_gemm<<<gemm_grid, 256, 0, stream>>>(
            x, lins_w + (size_t)r * DD * DD, DD,
            films_w + (size_t)r * DD * 2 * DD, 2 * DD,
            films_b + (size_t)r * 2 * DD,
            xl, beta, gamma);
        edge_pass<<<(EE + 7) / 8, 256, 0, stream>>>(ei, et, r, xl, beta, gamma,
                                                    cnt, out_acc);
    }

    final_gemm<<<gemm_grid, 256, 0, stream>>>(out_acc, linear1_w, linear1_b, out);
}

// Round 2
// 2557.459 us; speedup vs baseline: 3.3850x; 3.3850x over previous
//
#include <hip/hip_runtime.h>
#include <math.h>

// Problem constants
#define NN 100000
#define DD 128
#define EE 600000
#define RR 5

#define WSTR 136          // padded col stride (f16 elems) for transposed W / A tiles
#define HALF_SLOTS 192    // W column-slots resident in LDS per pass (of 384)
#define SLAB 32           // rows per A slab; 100000 = 3125 * 32 exactly
#define NSLAB (NN / SLAB) // 3125

typedef _Float16 v8h __attribute__((ext_vector_type(8)));
typedef _Float16 h4  __attribute__((ext_vector_type(4)));
typedef float    v4f __attribute__((ext_vector_type(4)));

__device__ __forceinline__ float gelu_exact(float v) {
    return 0.5f * v * (1.0f + erff(v * 0.7071067811865476f));
}

// ---------------------------------------------------------------------------
// x (fp32) -> xh (f16), row-major [NN][DD]
// ---------------------------------------------------------------------------
__global__ __launch_bounds__(256)
void convert_x(const float* __restrict__ x, _Float16* __restrict__ xh)
{
    size_t u = (size_t)blockIdx.x * 256 + threadIdx.x;   // one v8 unit per thread
    const float4 a = *(const float4*)(x + u * 8);
    const float4 b = *(const float4*)(x + u * 8 + 4);
    v8h o;
    o[0] = (_Float16)a.x; o[1] = (_Float16)a.y; o[2] = (_Float16)a.z; o[3] = (_Float16)a.w;
    o[4] = (_Float16)b.x; o[5] = (_Float16)b.y; o[6] = (_Float16)b.z; o[7] = (_Float16)b.w;
    *(v8h*)(xh + u * 8) = o;
}

// ---------------------------------------------------------------------------
// Transpose+convert all weights into ws as f16 col-major with stride WSTR.
// Slot layout per film set (384 slots): s = half*192 + a*64 + c
//   a=0 -> lin W col (half*64+c); a=1 -> beta col; a=2 -> gamma col.
// Sets: 0 = skip, 1..5 = relations, then 128 slots for linear1_w.
// One block (128 threads) per slot; thread k handles W[k][col].
// ---------------------------------------------------------------------------
__global__ __launch_bounds__(128)
void transpose_w(const float* __restrict__ lin_skip_w,
                 const float* __restrict__ film_skip_w,
                 const float* __restrict__ lins_w,
                 const float* __restrict__ films_w,
                 const float* __restrict__ linear1_w,
                 _Float16* __restrict__ wt)
{
    const int b = blockIdx.x;
    const int k = threadIdx.x;
    float v;
    _Float16* dst;
    if (b < 6 * 384) {
        const int set = b / 384;
        const int s   = b % 384;
        const int half = s / 192;
        const int rem  = s % 192;
        const int a    = rem / 64;
        const int col  = half * 64 + (rem % 64);   // within the array's 128 cols
        if (set == 0) {
            v = (a == 0) ? lin_skip_w[k * DD + col]
                         : film_skip_w[k * 2 * DD + (a - 1) * DD + col];
        } else {
            const int r = set - 1;
            v = (a == 0) ? lins_w[((size_t)r * DD + k) * DD + col]
                         : films_w[((size_t)r * DD + k) * 2 * DD + (a - 1) * DD + col];
        }
        dst = wt + (size_t)set * 384 * WSTR + (size_t)s * WSTR + k;
    } else {
        const int s = b - 6 * 384;                 // 0..127 = output col of linear1
        v = linear1_w[k * DD + s];
        dst = wt + (size_t)6 * 384 * WSTR + (size_t)s * WSTR + k;
    }
    *dst = (_Float16)v;
}

// ---------------------------------------------------------------------------
// per-(relation,dst) in-degree counts
// ---------------------------------------------------------------------------
__global__ __launch_bounds__(256)
void count_kernel(const int* __restrict__ ei, const int* __restrict__ et,
                  float* __restrict__ cnt)
{
    int e = blockIdx.x * 256 + threadIdx.x;
    if (e < EE) {
        int r = et[e];
        int d = ei[EE + e];
        atomicAdd(&cnt[(size_t)r * NN + d], 1.0f);
    }
}

// ---------------------------------------------------------------------------
// Persistent W-stationary MFMA GEMM producing, per 32-row slab:
//   xl = x@Wa, beta = x@Wb (+bias), gamma = x@Wg (+bias)
// Operands swapped (W as A-operand, x as B-operand) so each lane's 4 acc regs
// are 4 CONSECUTIVE output columns -> packed h4 (8B) stores.
// is_skip: fuse relu(gamma*xl+beta) -> out_acc (fp32), no intermediates.
// LDS: 192 slots * 136 * 2 = 52224 B (W half) + 32*136*2 = 8704 B (A) = 60928 B
// ---------------------------------------------------------------------------
__global__ __launch_bounds__(256)
void film_mfma(const _Float16* __restrict__ xh,
               const _Float16* __restrict__ Wt,     // [384][WSTR] slot-major
               const float* __restrict__ bias,      // films_b row (2D) or null
               _Float16* __restrict__ xl,
               _Float16* __restrict__ bh,
               _Float16* __restrict__ gh,
               float* __restrict__ out_acc,
               int is_skip)
{
    __shared__ _Float16 Wl[HALF_SLOTS * WSTR];
    __shared__ _Float16 Al[SLAB * WSTR];
    const int tid  = threadIdx.x;
    const int wv   = tid >> 6;
    const int lane = tid & 63;
    const int l15  = lane & 15;
    const int quad = lane >> 4;

    for (int half = 0; half < 2; ++half) {
        __syncthreads();   // prior half's LDS reads complete before Wl overwrite
        // stage W half: 26112 f16 = 3264 v8h units
        for (int u = tid; u < (HALF_SLOTS * WSTR) / 8; u += 256)
            *(v8h*)(Wl + (size_t)u * 8) =
                *(const v8h*)(Wt + (size_t)half * HALF_SLOTS * WSTR + (size_t)u * 8);

        const int c0 = half * 64 + wv * 16 + quad * 4;   // output col base (per array)
        float4 bb = make_float4(0.f, 0.f, 0.f, 0.f);
        float4 bg = make_float4(0.f, 0.f, 0.f, 0.f);
        if (!is_skip) {
            bb = *(const float4*)(bias + c0);
            bg = *(const float4*)(bias + DD + c0);
        }

        for (int s = blockIdx.x; s < NSLAB; s += gridDim.x) {
            __syncthreads();   // prior slab's Al reads (and W stage, first iter) done
            #pragma unroll
            for (int j = 0; j < 2; ++j) {
                int u = tid + j * 256;          // 0..511
                int row = u >> 4, c8 = u & 15;
                *(v8h*)(Al + row * WSTR + c8 * 8) =
                    *(const v8h*)(xh + ((size_t)s * SLAB + row) * DD + c8 * 8);
            }
            __syncthreads();

            v4f acc[3][2];
            #pragma unroll
            for (int a = 0; a < 3; ++a)
                #pragma unroll
                for (int rt = 0; rt < 2; ++rt)
                    acc[a][rt] = (v4f){0.f, 0.f, 0.f, 0.f};

            #pragma unroll
            for (int ks = 0; ks < 4; ++ks) {
                v8h xf0 = *(v8h*)(Al + l15 * WSTR + ks * 32 + quad * 8);
                v8h xf1 = *(v8h*)(Al + (16 + l15) * WSTR + ks * 32 + quad * 8);
                v8h wf[3];
                #pragma unroll
                for (int a = 0; a < 3; ++a)
                    wf[a] = *(v8h*)(Wl + (a * 64 + wv * 16 + l15) * WSTR + ks * 32 + quad * 8);
                #pragma unroll
                for (int a = 0; a < 3; ++a) {
                    acc[a][0] = __builtin_amdgcn_mfma_f32_16x16x32_f16(wf[a], xf0, acc[a][0], 0, 0, 0);
                    acc[a][1] = __builtin_amdgcn_mfma_f32_16x16x32_f16(wf[a], xf1, acc[a][1], 0, 0, 0);
                }
            }

            // epilogue: lane holds rows s*32+rt*16+l15, cols c0..c0+3 (per array)
            #pragma unroll
            for (int rt = 0; rt < 2; ++rt) {
                const size_t row = (size_t)s * SLAB + rt * 16 + l15;
                v4f xv = acc[0][rt], bv = acc[1][rt], gv = acc[2][rt];
                if (is_skip) {
                    float4 o;
                    o.x = fmaxf(gv[0] * xv[0] + bv[0], 0.f);
                    o.y = fmaxf(gv[1] * xv[1] + bv[1], 0.f);
                    o.z = fmaxf(gv[2] * xv[2] + bv[2], 0.f);
                    o.w = fmaxf(gv[3] * xv[3] + bv[3], 0.f);
                    *(float4*)(out_acc + row * DD + c0) = o;
                } else {
                    h4 ox, ob, og;
                    ox[0] = (_Float16)xv[0]; ox[1] = (_Float16)xv[1];
                    ox[2] = (_Float16)xv[2]; ox[3] = (_Float16)xv[3];
                    ob[0] = (_Float16)(bv[0] + bb.x); ob[1] = (_Float16)(bv[1] + bb.y);
                    ob[2] = (_Float16)(bv[2] + bb.z); ob[3] = (_Float16)(bv[3] + bb.w);
                    og[0] = (_Float16)(gv[0] + bg.x); og[1] = (_Float16)(gv[1] + bg.y);
                    og[2] = (_Float16)(gv[2] + bg.z); og[3] = (_Float16)(gv[3] + bg.w);
                    *(h4*)(xl + row * DD + c0) = ox;
                    *(h4*)(bh + row * DD + c0) = ob;
                    *(h4*)(gh + row * DD + c0) = og;
                }
            }
        }
    }
}

// ---------------------------------------------------------------------------
// 16 lanes per edge; f16 gathers, fp32 atomics into out_acc.
// ---------------------------------------------------------------------------
__global__ __launch_bounds__(256)
void edge_pass(const int* __restrict__ ei, const int* __restrict__ et, int rel,
               const _Float16* __restrict__ xl, const _Float16* __restrict__ bh,
               const _Float16* __restrict__ gh, const float* __restrict__ cnt,
               float* __restrict__ out_acc)
{
    int e = blockIdx.x * 16 + (threadIdx.x >> 4);
    if (e >= EE) return;
    if (et[e] != rel) return;
    const int src = ei[e];
    const int dst = ei[EE + e];
    const int c0 = (threadIdx.x & 15) * 8;
    const float inv = 1.0f / fmaxf(cnt[(size_t)rel * NN + dst], 1.0f);
    v8h xs = *(const v8h*)(xl + (size_t)src * DD + c0);
    v8h gs = *(const v8h*)(gh + (size_t)dst * DD + c0);
    v8h bs = *(const v8h*)(bh + (size_t)dst * DD + c0);
    float* dp = out_acc + (size_t)dst * DD + c0;
    #pragma unroll
    for (int j = 0; j < 8; ++j) {
        float m = fmaxf((float)gs[j] * (float)xs[j] + (float)bs[j], 0.f) * inv;
        atomicAdd(dp + j, m);
    }
}

// ---------------------------------------------------------------------------
// out = gelu(out_acc) @ linear1_w + linear1_b, W-stationary MFMA.
// LDS: 128*136*2 = 34816 (W) + 8704 (A) = 43520 B
// ---------------------------------------------------------------------------
__global__ __launch_bounds__(256)
void final_mfma(const float* __restrict__ out_acc,
                const _Float16* __restrict__ Wt,    // [128][WSTR]
                const float* __restrict__ bias,
                float* __restrict__ out)
{
    __shared__ _Float16 Wl[DD * WSTR];
    __shared__ _Float16 Al[SLAB * WSTR];
    const int tid  = threadIdx.x;
    const int wv   = tid >> 6;
    const int lane = tid & 63;
    const int l15  = lane & 15;
    const int quad = lane >> 4;

    for (int u = tid; u < (DD * WSTR) / 8; u += 256)
        *(v8h*)(Wl + (size_t)u * 8) = *(const v8h*)(Wt + (size_t)u * 8);

    float4 bf[2];
    #pragma unroll
    for (int ct = 0; ct < 2; ++ct)
        bf[ct] = *(const float4*)(bias + wv * 32 + ct * 16 + quad * 4);

    for (int s = blockIdx.x; s < NSLAB; s += gridDim.x) {
        __syncthreads();
        #pragma unroll
        for (int j = 0; j < 4; ++j) {
            int u = tid + j * 256;              // 0..1023
            int row = u >> 5, c = (u & 31) * 4;
            float4 g = *(const float4*)(out_acc + ((size_t)s * SLAB + row) * DD + c);
            h4 o;
            o[0] = (_Float16)gelu_exact(g.x);
            o[1] = (_Float16)gelu_exact(g.y);
            o[2] = (_Float16)gelu_exact(g.z);
            o[3] = (_Float16)gelu_exact(g.w);
            *(h4*)(Al + row * WSTR + c) = o;
        }
        __syncthreads();

        v4f acc[2][2];
        #pragma unroll
        for (int ct = 0; ct < 2; ++ct)
            #pragma unroll
            for (int rt = 0; rt < 2; ++rt)
                acc[ct][rt] = (v4f){0.f, 0.f, 0.f, 0.f};

        #pragma unroll
        for (int ks = 0; ks < 4; ++ks) {
            v8h xf0 = *(v8h*)(Al + l15 * WSTR + ks * 32 + quad * 8);
            v8h xf1 = *(v8h*)(Al + (16 + l15) * WSTR + ks * 32 + quad * 8);
            v8h wf[2];
            #pragma unroll
            for (int ct = 0; ct < 2; ++ct)
                wf[ct] = *(v8h*)(Wl + (wv * 32 + ct * 16 + l15) * WSTR + ks * 32 + quad * 8);
            #pragma unroll
            for (int ct = 0; ct < 2; ++ct) {
                acc[ct][0] = __builtin_amdgcn_mfma_f32_16x16x32_f16(wf[ct], xf0, acc[ct][0], 0, 0, 0);
                acc[ct][1] = __builtin_amdgcn_mfma_f32_16x16x32_f16(wf[ct], xf1, acc[ct][1], 0, 0, 0);
            }
        }

        #pragma unroll
        for (int ct = 0; ct < 2; ++ct)
            #pragma unroll
            for (int rt = 0; rt < 2; ++rt) {
                const size_t row = (size_t)s * SLAB + rt * 16 + l15;
                const int c0 = wv * 32 + ct * 16 + quad * 4;
                float4 o;
                o.x = acc[ct][rt][0] + bf[ct].x;
                o.y = acc[ct][rt][1] + bf[ct].y;
                o.z = acc[ct][rt][2] + bf[ct].z;
                o.w = acc[ct][rt][3] + bf[ct].w;
                *(float4*)(out + row * DD + c0) = o;
            }
    }
}

extern "C" void kernel_launch(void* const* d_in, const int* in_sizes, int n_in,
                              void* d_out, int out_size, void* d_ws, size_t ws_size,
                              hipStream_t stream)
{
    const float* x           = (const float*)d_in[0];
    const int*   ei          = (const int*)d_in[1];
    const int*   et          = (const int*)d_in[2];
    const float* lin_skip_w  = (const float*)d_in[3];
    const float* film_skip_w = (const float*)d_in[4];
    const float* lins_w      = (const float*)d_in[5];
    const float* films_w     = (const float*)d_in[6];
    const float* films_b     = (const float*)d_in[7];
    const float* linear1_w   = (const float*)d_in[8];
    const float* linear1_b   = (const float*)d_in[9];
    float* out = (float*)d_out;
    char*  ws  = (char*)d_ws;

    // workspace layout (bytes, all 256-aligned)
    _Float16* xh  = (_Float16*)(ws);                       // 25,600,000
    _Float16* wt  = (_Float16*)(ws + 25600000);            //    661,504
    _Float16* xl  = (_Float16*)(ws + 26261504);            // 25,600,000
    _Float16* bh  = (_Float16*)(ws + 51861504);            // 25,600,000
    _Float16* gh  = (_Float16*)(ws + 77461504);            // 25,600,000
    float*    oa  = (float*)   (ws + 103061504);           // 51,200,000
    float*    cnt = (float*)   (ws + 154261504);           //  2,000,000

    convert_x<<<6250, 256, 0, stream>>>(x, xh);
    transpose_w<<<6 * 384 + 128, 128, 0, stream>>>(lin_skip_w, film_skip_w,
                                                   lins_w, films_w, linear1_w, wt);
    hipMemsetAsync(cnt, 0, (size_t)RR * NN * sizeof(float), stream);
    count_kernel<<<(EE + 255) / 256, 256, 0, stream>>>(ei, et, cnt);

    // skip path: fused relu(gamma*xl+beta) -> out_acc
    film_mfma<<<512, 256, 0, stream>>>(xh, wt, nullptr, nullptr, nullptr, nullptr,
                                       oa, 1);

    for (int r = 0; r < RR; ++r) {
        film_mfma<<<512, 256, 0, stream>>>(
            xh, wt + (size_t)(r + 1) * 384 * WSTR, films_b + (size_t)r * 2 * DD,
            xl, bh, gh, nullptr, 0);
        edge_pass<<<EE / 16, 256, 0, stream>>>(ei, et, r, xl, bh, gh, cnt, oa);
    }

    final_mfma<<<512, 256, 0, stream>>>(oa, wt + (size_t)6 * 384 * WSTR,
                                        linear1_b, out);
}

// Round 3
// 523.963 us; speedup vs baseline: 16.5222x; 4.8810x over previous
//
#include <hip/hip_runtime.h>
#include <math.h>

// Problem constants
#define NN 100000
#define DD 128
#define EE 600000
#define RR 5
#define MCNT (RR * NN)          // 500000 sort buckets
#define NB1 489                 // ceil(MCNT / 1024) blocks for level-1 scan

#define WSTR 136          // padded col stride (f16 elems) for transposed W / A tiles
#define HALF_SLOTS 192    // W column-slots resident in LDS per pass (of 384)
#define SLAB 32           // rows per A slab; 100000 = 3125 * 32 exactly
#define NSLAB (NN / SLAB) // 3125

typedef _Float16 v8h __attribute__((ext_vector_type(8)));
typedef _Float16 h4  __attribute__((ext_vector_type(4)));
typedef float    v4f __attribute__((ext_vector_type(4)));

__device__ __forceinline__ float gelu_exact(float v) {
    return 0.5f * v * (1.0f + erff(v * 0.7071067811865476f));
}

// ---------------------------------------------------------------------------
// x (fp32) -> xh (f16), row-major [NN][DD]
// ---------------------------------------------------------------------------
__global__ __launch_bounds__(256)
void convert_x(const float* __restrict__ x, _Float16* __restrict__ xh)
{
    size_t u = (size_t)blockIdx.x * 256 + threadIdx.x;
    const float4 a = *(const float4*)(x + u * 8);
    const float4 b = *(const float4*)(x + u * 8 + 4);
    v8h o;
    o[0] = (_Float16)a.x; o[1] = (_Float16)a.y; o[2] = (_Float16)a.z; o[3] = (_Float16)a.w;
    o[4] = (_Float16)b.x; o[5] = (_Float16)b.y; o[6] = (_Float16)b.z; o[7] = (_Float16)b.w;
    *(v8h*)(xh + u * 8) = o;
}

// ---------------------------------------------------------------------------
// Transpose+convert all weights into ws as f16 col-major with stride WSTR.
// ---------------------------------------------------------------------------
__global__ __launch_bounds__(128)
void transpose_w(const float* __restrict__ lin_skip_w,
                 const float* __restrict__ film_skip_w,
                 const float* __restrict__ lins_w,
                 const float* __restrict__ films_w,
                 const float* __restrict__ linear1_w,
                 _Float16* __restrict__ wt)
{
    const int b = blockIdx.x;
    const int k = threadIdx.x;
    float v;
    _Float16* dst;
    if (b < 6 * 384) {
        const int set = b / 384;
        const int s   = b % 384;
        const int half = s / 192;
        const int rem  = s % 192;
        const int a    = rem / 64;
        const int col  = half * 64 + (rem % 64);
        if (set == 0) {
            v = (a == 0) ? lin_skip_w[k * DD + col]
                         : film_skip_w[k * 2 * DD + (a - 1) * DD + col];
        } else {
            const int r = set - 1;
            v = (a == 0) ? lins_w[((size_t)r * DD + k) * DD + col]
                         : films_w[((size_t)r * DD + k) * 2 * DD + (a - 1) * DD + col];
        }
        dst = wt + (size_t)set * 384 * WSTR + (size_t)s * WSTR + k;
    } else {
        const int s = b - 6 * 384;
        v = linear1_w[k * DD + s];
        dst = wt + (size_t)6 * 384 * WSTR + (size_t)s * WSTR + k;
    }
    *dst = (_Float16)v;
}

// ---------------------------------------------------------------------------
// Counting sort of edges by key = rel*NN + dst.
// ---------------------------------------------------------------------------
__global__ __launch_bounds__(256)
void count_kernel(const int* __restrict__ ei, const int* __restrict__ et,
                  int* __restrict__ cnt)
{
    int e = blockIdx.x * 256 + threadIdx.x;
    if (e < EE) atomicAdd(&cnt[(size_t)et[e] * NN + ei[EE + e]], 1);
}

// level-1 scan: each block handles 1024 elems (4/thread); writes per-element
// exclusive-within-block prefix to `partial`, block total to `bsum`.
__global__ __launch_bounds__(256)
void scan1(const int* __restrict__ cnt, int* __restrict__ partial,
           int* __restrict__ bsum)
{
    __shared__ int s[256];
    const int t = threadIdx.x;
    const int base = blockIdx.x * 1024 + t * 4;
    int v[4], sum = 0;
    #pragma unroll
    for (int j = 0; j < 4; ++j) {
        v[j] = (base + j < MCNT) ? cnt[base + j] : 0;
        sum += v[j];
    }
    s[t] = sum;
    __syncthreads();
    for (int off = 1; off < 256; off <<= 1) {
        int x = (t >= off) ? s[t - off] : 0;
        __syncthreads();
        s[t] += x;
        __syncthreads();
    }
    int run = s[t] - sum;          // exclusive prefix of this thread's chunk
    if (t == 255) bsum[blockIdx.x] = s[255];
    #pragma unroll
    for (int j = 0; j < 4; ++j) {
        if (base + j < MCNT) partial[base + j] = run;
        run += v[j];
    }
}

// level-2: exclusive scan of the NB1 block sums (single block, 512 threads)
__global__ __launch_bounds__(512)
void scan2(const int* __restrict__ bsum, int* __restrict__ bsum2)
{
    __shared__ int s[512];
    const int t = threadIdx.x;
    const int v = (t < NB1) ? bsum[t] : 0;
    s[t] = v;
    __syncthreads();
    for (int off = 1; off < 512; off <<= 1) {
        int x = (t >= off) ? s[t - off] : 0;
        __syncthreads();
        s[t] += x;
        __syncthreads();
    }
    if (t < NB1) bsum2[t] = s[t] - v;
}

// level-3: rowptr[idx] = head[idx] = partial[idx] + bsum2[block]; rowptr[M]=EE
__global__ __launch_bounds__(256)
void scan3(const int* __restrict__ partial, const int* __restrict__ bsum2,
           int* __restrict__ rowptr, int* __restrict__ head)
{
    const int t = threadIdx.x;
    const int base = blockIdx.x * 1024 + t * 4;
    const int add = bsum2[blockIdx.x];
    #pragma unroll
    for (int j = 0; j < 4; ++j) {
        if (base + j < MCNT) {
            int v = partial[base + j] + add;
            rowptr[base + j] = v;
            head[base + j]   = v;
        }
    }
    if (blockIdx.x == 0 && t == 0) rowptr[MCNT] = EE;
}

// scatter src ids into bucket order
__global__ __launch_bounds__(256)
void scatter_kernel(const int* __restrict__ ei, const int* __restrict__ et,
                    int* __restrict__ head, int* __restrict__ srcs)
{
    int e = blockIdx.x * 256 + threadIdx.x;
    if (e < EE) {
        int pos = atomicAdd(&head[(size_t)et[e] * NN + ei[EE + e]], 1);
        srcs[pos] = ei[e];
    }
}

// ---------------------------------------------------------------------------
// Persistent W-stationary MFMA GEMM (unchanged from round 2).
// ---------------------------------------------------------------------------
__global__ __launch_bounds__(256)
void film_mfma(const _Float16* __restrict__ xh,
               const _Float16* __restrict__ Wt,
               const float* __restrict__ bias,
               _Float16* __restrict__ xl,
               _Float16* __restrict__ bh,
               _Float16* __restrict__ gh,
               float* __restrict__ out_acc,
               int is_skip)
{
    __shared__ _Float16 Wl[HALF_SLOTS * WSTR];
    __shared__ _Float16 Al[SLAB * WSTR];
    const int tid  = threadIdx.x;
    const int wv   = tid >> 6;
    const int lane = tid & 63;
    const int l15  = lane & 15;
    const int quad = lane >> 4;

    for (int half = 0; half < 2; ++half) {
        __syncthreads();
        for (int u = tid; u < (HALF_SLOTS * WSTR) / 8; u += 256)
            *(v8h*)(Wl + (size_t)u * 8) =
                *(const v8h*)(Wt + (size_t)half * HALF_SLOTS * WSTR + (size_t)u * 8);

        const int c0 = half * 64 + wv * 16 + quad * 4;
        float4 bb = make_float4(0.f, 0.f, 0.f, 0.f);
        float4 bg = make_float4(0.f, 0.f, 0.f, 0.f);
        if (!is_skip) {
            bb = *(const float4*)(bias + c0);
            bg = *(const float4*)(bias + DD + c0);
        }

        for (int s = blockIdx.x; s < NSLAB; s += gridDim.x) {
            __syncthreads();
            #pragma unroll
            for (int j = 0; j < 2; ++j) {
                int u = tid + j * 256;
                int row = u >> 4, c8 = u & 15;
                *(v8h*)(Al + row * WSTR + c8 * 8) =
                    *(const v8h*)(xh + ((size_t)s * SLAB + row) * DD + c8 * 8);
            }
            __syncthreads();

            v4f acc[3][2];
            #pragma unroll
            for (int a = 0; a < 3; ++a)
                #pragma unroll
                for (int rt = 0; rt < 2; ++rt)
                    acc[a][rt] = (v4f){0.f, 0.f, 0.f, 0.f};

            #pragma unroll
            for (int ks = 0; ks < 4; ++ks) {
                v8h xf0 = *(v8h*)(Al + l15 * WSTR + ks * 32 + quad * 8);
                v8h xf1 = *(v8h*)(Al + (16 + l15) * WSTR + ks * 32 + quad * 8);
                v8h wf[3];
                #pragma unroll
                for (int a = 0; a < 3; ++a)
                    wf[a] = *(v8h*)(Wl + (a * 64 + wv * 16 + l15) * WSTR + ks * 32 + quad * 8);
                #pragma unroll
                for (int a = 0; a < 3; ++a) {
                    acc[a][0] = __builtin_amdgcn_mfma_f32_16x16x32_f16(wf[a], xf0, acc[a][0], 0, 0, 0);
                    acc[a][1] = __builtin_amdgcn_mfma_f32_16x16x32_f16(wf[a], xf1, acc[a][1], 0, 0, 0);
                }
            }

            #pragma unroll
            for (int rt = 0; rt < 2; ++rt) {
                const size_t row = (size_t)s * SLAB + rt * 16 + l15;
                v4f xv = acc[0][rt], bv = acc[1][rt], gv = acc[2][rt];
                if (is_skip) {
                    float4 o;
                    o.x = fmaxf(gv[0] * xv[0] + bv[0], 0.f);
                    o.y = fmaxf(gv[1] * xv[1] + bv[1], 0.f);
                    o.z = fmaxf(gv[2] * xv[2] + bv[2], 0.f);
                    o.w = fmaxf(gv[3] * xv[3] + bv[3], 0.f);
                    *(float4*)(out_acc + row * DD + c0) = o;
                } else {
                    h4 ox, ob, og;
                    ox[0] = (_Float16)xv[0]; ox[1] = (_Float16)xv[1];
                    ox[2] = (_Float16)xv[2]; ox[3] = (_Float16)xv[3];
                    ob[0] = (_Float16)(bv[0] + bb.x); ob[1] = (_Float16)(bv[1] + bb.y);
                    ob[2] = (_Float16)(bv[2] + bb.z); ob[3] = (_Float16)(bv[3] + bb.w);
                    og[0] = (_Float16)(gv[0] + bg.x); og[1] = (_Float16)(gv[1] + bg.y);
                    og[2] = (_Float16)(gv[2] + bg.z); og[3] = (_Float16)(gv[3] + bg.w);
                    *(h4*)(xl + row * DD + c0) = ox;
                    *(h4*)(bh + row * DD + c0) = ob;
                    *(h4*)(gh + row * DD + c0) = og;
                }
            }
        }
    }
}

// ---------------------------------------------------------------------------
// Owner-computes aggregation: one 16-lane group per dst node. Reads its
// contiguous src list for this relation, accumulates relu(g*x+b) in regs,
// single non-atomic RMW into out_acc (group exclusively owns dst this pass).
// ---------------------------------------------------------------------------
__global__ __launch_bounds__(256)
void agg_pass(const int* __restrict__ rowptr_rel,   // rowptr + rel*NN
              const int* __restrict__ srcs,
              const _Float16* __restrict__ xl, const _Float16* __restrict__ bh,
              const _Float16* __restrict__ gh, float* __restrict__ out_acc)
{
    const int d = blockIdx.x * 16 + (threadIdx.x >> 4);
    if (d >= NN) return;
    const int start = rowptr_rel[d];
    const int end   = rowptr_rel[d + 1];
    if (start == end) return;
    const int c0 = (threadIdx.x & 15) * 8;
    const v8h gs = *(const v8h*)(gh + (size_t)d * DD + c0);
    const v8h bs = *(const v8h*)(bh + (size_t)d * DD + c0);
    float acc[8] = {0.f, 0.f, 0.f, 0.f, 0.f, 0.f, 0.f, 0.f};
    for (int p = start; p < end; ++p) {
        const int src = srcs[p];
        const v8h xs = *(const v8h*)(xl + (size_t)src * DD + c0);
        #pragma unroll
        for (int j = 0; j < 8; ++j)
            acc[j] += fmaxf((float)gs[j] * (float)xs[j] + (float)bs[j], 0.f);
    }
    const float inv = 1.0f / (float)(end - start);
    float* dp = out_acc + (size_t)d * DD + c0;
    float4 o0 = *(float4*)dp;
    float4 o1 = *(float4*)(dp + 4);
    o0.x += acc[0] * inv; o0.y += acc[1] * inv;
    o0.z += acc[2] * inv; o0.w += acc[3] * inv;
    o1.x += acc[4] * inv; o1.y += acc[5] * inv;
    o1.z += acc[6] * inv; o1.w += acc[7] * inv;
    *(float4*)dp       = o0;
    *(float4*)(dp + 4) = o1;
}

// ---------------------------------------------------------------------------
// out = gelu(out_acc) @ linear1_w + linear1_b  (unchanged from round 2)
// ---------------------------------------------------------------------------
__global__ __launch_bounds__(256)
void final_mfma(const float* __restrict__ out_acc,
                const _Float16* __restrict__ Wt,
                const float* __restrict__ bias,
                float* __restrict__ out)
{
    __shared__ _Float16 Wl[DD * WSTR];
    __shared__ _Float16 Al[SLAB * WSTR];
    const int tid  = threadIdx.x;
    const int wv   = tid >> 6;
    const int lane = tid & 63;
    const int l15  = lane & 15;
    const int quad = lane >> 4;

    for (int u = tid; u < (DD * WSTR) / 8; u += 256)
        *(v8h*)(Wl + (size_t)u * 8) = *(const v8h*)(Wt + (size_t)u * 8);

    float4 bf[2];
    #pragma unroll
    for (int ct = 0; ct < 2; ++ct)
        bf[ct] = *(const float4*)(bias + wv * 32 + ct * 16 + quad * 4);

    for (int s = blockIdx.x; s < NSLAB; s += gridDim.x) {
        __syncthreads();
        #pragma unroll
        for (int j = 0; j < 4; ++j) {
            int u = tid + j * 256;
            int row = u >> 5, c = (u & 31) * 4;
            float4 g = *(const float4*)(out_acc + ((size_t)s * SLAB + row) * DD + c);
            h4 o;
            o[0] = (_Float16)gelu_exact(g.x);
            o[1] = (_Float16)gelu_exact(g.y);
            o[2] = (_Float16)gelu_exact(g.z);
            o[3] = (_Float16)gelu_exact(g.w);
            *(h4*)(Al + row * WSTR + c) = o;
        }
        __syncthreads();

        v4f acc[2][2];
        #pragma unroll
        for (int ct = 0; ct < 2; ++ct)
            #pragma unroll
            for (int rt = 0; rt < 2; ++rt)
                acc[ct][rt] = (v4f){0.f, 0.f, 0.f, 0.f};

        #pragma unroll
        for (int ks = 0; ks < 4; ++ks) {
            v8h xf0 = *(v8h*)(Al + l15 * WSTR + ks * 32 + quad * 8);
            v8h xf1 = *(v8h*)(Al + (16 + l15) * WSTR + ks * 32 + quad * 8);
            v8h wf[2];
            #pragma unroll
            for (int ct = 0; ct < 2; ++ct)
                wf[ct] = *(v8h*)(Wl + (wv * 32 + ct * 16 + l15) * WSTR + ks * 32 + quad * 8);
            #pragma unroll
            for (int ct = 0; ct < 2; ++ct) {
                acc[ct][0] = __builtin_amdgcn_mfma_f32_16x16x32_f16(wf[ct], xf0, acc[ct][0], 0, 0, 0);
                acc[ct][1] = __builtin_amdgcn_mfma_f32_16x16x32_f16(wf[ct], xf1, acc[ct][1], 0, 0, 0);
            }
        }

        #pragma unroll
        for (int ct = 0; ct < 2; ++ct)
            #pragma unroll
            for (int rt = 0; rt < 2; ++rt) {
                const size_t row = (size_t)s * SLAB + rt * 16 + l15;
                const int c0 = wv * 32 + ct * 16 + quad * 4;
                float4 o;
                o.x = acc[ct][rt][0] + bf[ct].x;
                o.y = acc[ct][rt][1] + bf[ct].y;
                o.z = acc[ct][rt][2] + bf[ct].z;
                o.w = acc[ct][rt][3] + bf[ct].w;
                *(float4*)(out + row * DD + c0) = o;
            }
    }
}

extern "C" void kernel_launch(void* const* d_in, const int* in_sizes, int n_in,
                              void* d_out, int out_size, void* d_ws, size_t ws_size,
                              hipStream_t stream)
{
    const float* x           = (const float*)d_in[0];
    const int*   ei          = (const int*)d_in[1];
    const int*   et          = (const int*)d_in[2];
    const float* lin_skip_w  = (const float*)d_in[3];
    const float* film_skip_w = (const float*)d_in[4];
    const float* lins_w      = (const float*)d_in[5];
    const float* films_w     = (const float*)d_in[6];
    const float* films_b     = (const float*)d_in[7];
    const float* linear1_w   = (const float*)d_in[8];
    const float* linear1_b   = (const float*)d_in[9];
    float* out = (float*)d_out;
    char*  ws  = (char*)d_ws;

    // workspace layout (bytes, 256-aligned)
    _Float16* xh      = (_Float16*)(ws);                   // 25,600,000
    _Float16* wt      = (_Float16*)(ws + 25600000);        //    661,504
    _Float16* xl      = (_Float16*)(ws + 26261504);        // 25,600,000
    _Float16* bh      = (_Float16*)(ws + 51861504);        // 25,600,000
    _Float16* gh      = (_Float16*)(ws + 77461504);        // 25,600,000
    float*    oa      = (float*)   (ws + 103061504);       // 51,200,000
    int*      cnt     = (int*)     (ws + 154261504);       //  2,000,000
    int*      partial = (int*)     (ws + 156261504);       //  2,000,000
    int*      rowptr  = (int*)     (ws + 158261504);       //  2,000,128
    int*      head    = (int*)     (ws + 160261632);       //  2,000,000
    int*      srcs    = (int*)     (ws + 162261632);       //  2,400,000
    int*      bsum    = (int*)     (ws + 164661632);       //      4,096
    int*      bsum2   = (int*)     (ws + 164665728);       //      4,096

    convert_x<<<6250, 256, 0, stream>>>(x, xh);
    transpose_w<<<6 * 384 + 128, 128, 0, stream>>>(lin_skip_w, film_skip_w,
                                                   lins_w, films_w, linear1_w, wt);

    // counting sort of edges by (rel, dst)
    hipMemsetAsync(cnt, 0, (size_t)MCNT * sizeof(int), stream);
    count_kernel<<<(EE + 255) / 256, 256, 0, stream>>>(ei, et, cnt);
    scan1<<<NB1, 256, 0, stream>>>(cnt, partial, bsum);
    scan2<<<1, 512, 0, stream>>>(bsum, bsum2);
    scan3<<<NB1, 256, 0, stream>>>(partial, bsum2, rowptr, head);
    scatter_kernel<<<(EE + 255) / 256, 256, 0, stream>>>(ei, et, head, srcs);

    // skip path: fused relu(gamma*xl+beta) -> out_acc
    film_mfma<<<512, 256, 0, stream>>>(xh, wt, nullptr, nullptr, nullptr, nullptr,
                                       oa, 1);

    for (int r = 0; r < RR; ++r) {
        film_mfma<<<512, 256, 0, stream>>>(
            xh, wt + (size_t)(r + 1) * 384 * WSTR, films_b + (size_t)r * 2 * DD,
            xl, bh, gh, nullptr, 0);
        agg_pass<<<(NN + 15) / 16, 256, 0, stream>>>(rowptr + (size_t)r * NN,
                                                     srcs, xl, bh, gh, oa);
    }

    final_mfma<<<512, 256, 0, stream>>>(oa, wt + (size_t)6 * 384 * WSTR,
                                        linear1_b, out);
}